// Round 11
// baseline (5757.314 us; speedup 1.0000x reference)
//
#include <hip/hip_runtime.h>
#include <hip/hip_bf16.h>

// Problem dims
#define S_LEN 128
#define M_B   256
#define E_DIM 1024
#define H_DIM 512
#define G4    2048          // 4*H
#define N_ROWS (S_LEN*M_B)  // 32768

typedef __bf16 bf16_t;
typedef __bf16 bf16x8 __attribute__((ext_vector_type(8)));
typedef float  f32x4  __attribute__((ext_vector_type(4)));
typedef int    i32x4  __attribute__((ext_vector_type(4)));

#define AS1(p) ((const __attribute__((address_space(1))) void*)(p))
#define AS3(p) ((__attribute__((address_space(3))) void*)(p))

__device__ __forceinline__ float sigm(float x)     { return 1.f / (1.f + __expf(-x)); }
__device__ __forceinline__ float tanhfast(float x) { return 2.f / (1.f + __expf(-2.f * x)) - 1.f; }

// Device-scope (LLC) h exchange: write-through stores, cache-bypassing loads.
__device__ __forceinline__ void store_h_dev(bf16_t* p, bf16_t v) {
    unsigned int w = (unsigned int)__builtin_bit_cast(unsigned short, v);
    asm volatile("global_store_short %0, %1, off sc0 sc1" :: "v"(p), "v"(w) : "memory");
}
__device__ __forceinline__ bf16x8 load_h_dev(const bf16_t* p) {
    i32x4 r;
    asm volatile("global_load_dwordx4 %0, %1, off sc0 sc1" : "=v"(r) : "v"(p) : "memory");
    return __builtin_bit_cast(bf16x8, r);
}

// ---------------------------------------------------------------------------
// Weight permutation + bf16 conversion, BOTH layers in one launch.
// Gate permutation: j' = q*64 + gate*16 + u16  <->  j = gate*512 + (q*16+u16)
// ---------------------------------------------------------------------------
__global__ __launch_bounds__(256)
void permute_all_kernel(const float* __restrict__ Wih0, const float* __restrict__ Whh0,
                        const float* __restrict__ b0,
                        const float* __restrict__ Wih1, const float* __restrict__ Whh1,
                        const float* __restrict__ b1,
                        bf16_t* __restrict__ Wih0p, bf16_t* __restrict__ Whh0p,
                        bf16_t* __restrict__ Wih1p, bf16_t* __restrict__ Whh1p,
                        float* __restrict__ b0p, float* __restrict__ b1p)
{
    int bid = blockIdx.x;            // lay*4096 + d*2048 + jp
    int lay = bid >> 12;
    int d   = (bid >> 11) & 1;
    int jp  = bid & 2047;
    int q = jp >> 6, r = jp & 63;
    int gate = r >> 4, u16 = r & 15;
    int j = gate * H_DIM + q * 16 + u16;

    const float* Wih = lay ? Wih1 : Wih0;
    const float* Whh = lay ? Whh1 : Whh0;
    const float* b   = lay ? b1 : b0;
    bf16_t* Wihp = lay ? Wih1p : Wih0p;
    bf16_t* Whhp = lay ? Whh1p : Whh0p;
    float*  bp   = lay ? b1p : b0p;

    const float* s_ih = Wih + ((size_t)d * G4 + j) * E_DIM;
    bf16_t*      d_ih = Wihp + ((size_t)d * G4 + jp) * E_DIM;
    for (int e = threadIdx.x; e < E_DIM; e += 256) d_ih[e] = (bf16_t)s_ih[e];

    const float* s_hh = Whh + ((size_t)d * G4 + j) * H_DIM;
    bf16_t*      d_hh = Whhp + ((size_t)d * G4 + jp) * H_DIM;
    for (int k = threadIdx.x; k < H_DIM; k += 256) d_hh[k] = (bf16_t)s_hh[k];

    if (threadIdx.x == 0) bp[d * G4 + jp] = b[d * G4 + j];
}

// ---------------------------------------------------------------------------
// Embedding lookup -> bf16 X (32768 x 1024). emb[PAD_ID] is zero.
// ---------------------------------------------------------------------------
__global__ __launch_bounds__(256)
void embed_kernel(const int* __restrict__ F, const float* __restrict__ emb,
                  bf16_t* __restrict__ X)
{
    int n   = blockIdx.x;            // t*256 + m
    int tok = F[n];
    const float4* src = (const float4*)(emb + (size_t)tok * E_DIM);
    bf16_t*       dst = X + (size_t)n * E_DIM;
    for (int i = threadIdx.x; i < E_DIM / 4; i += 256) {
        float4 v = src[i];
        dst[i * 4 + 0] = (bf16_t)v.x;
        dst[i * 4 + 1] = (bf16_t)v.y;
        dst[i * 4 + 2] = (bf16_t)v.z;
        dst[i * 4 + 3] = (bf16_t)v.w;
    }
}

// ---------------------------------------------------------------------------
// Persistent full-layer recurrence kernel with FUSED x-projection.
// Grid (32,4,2) = 256 blocks; block owns 64 gate-cols x 64 m-rows, dir d.
// Critical path per step (EXACT R6 structure): h loads (sc0sc1) -> h-MFMAs
// (Whh from LDS, swizzled) -> cell -> h stores -> drain -> signal.
// Shadow phase (overlaps barrier poll): out stores + x-projection of step
// t+1 (X rows + Wih slice streamed from L2/L3 into acc via MFMA).
// t==0 SKIPS the h-load+MFMA (h_prev=0): no dependence on hb buffer init,
// which also makes the layer-1 launch safe without re-zeroing hbA.
// ---------------------------------------------------------------------------
__global__ __launch_bounds__(256)
void lstm_layer_kernel(const bf16_t* __restrict__ Whhp,  // (2,2048,512) bf16
                       const bf16_t* __restrict__ Wihp,  // (2,2048,1024) bf16
                       const float* __restrict__ bp,     // (2,2048)
                       const bf16_t* __restrict__ Xin,   // (32768,1024) bf16
                       const int* __restrict__ F_lens,
                       bf16_t* __restrict__ hbA,         // (2,256,512) bf16
                       bf16_t* __restrict__ hbB,         // (2,256,512) bf16
                       bf16_t* __restrict__ H1,          // (32768,1024) bf16 (mode 0)
                       float* __restrict__ OUT,          // (32768,1024) f32  (mode 1)
                       unsigned int* __restrict__ ctr,   // 8 group counters, 64B apart
                       int mode, int s_base)
{
    const int TC = S_LEN;
    const int d  = blockIdx.z;
    const int bx = blockIdx.x;          // unit group 0..31
    const int m0 = blockIdx.y * 64;
    const int tid = threadIdx.x;
    const int lane = tid & 63, wave = tid >> 6;
    const int fr = lane & 15, fq = lane >> 4;
    const int gslot = ((blockIdx.y << 1) | d) * 16;   // 64B-spaced counter

    __shared__ __attribute__((aligned(16))) bf16_t Bt[64 * 512];   // 64 KiB

    // Stage Whh slice (64 rows x 512 K) once; XOR-swizzled SOURCE, linear dest.
    const bf16_t* Bg = Whhp + ((size_t)d * G4 + bx * 64) * H_DIM;
#pragma unroll
    for (int it = 0; it < 16; ++it) {
        int c   = it * 256 + tid;
        int row = c >> 6, ck = c & 63;
        int cks = ck ^ (row & 7);
        __builtin_amdgcn_global_load_lds(AS1(Bg + (size_t)row * H_DIM + cks * 8),
                                         AS3(&Bt[(it * 256 + wave * 64) * 8]), 16, 0, 0);
    }

    // Per-lane constants.
    const int mrow  = m0 + wave * 16 + fr;     // A-fragment row (h and x)
    const int u     = bx * 16 + fr;
    const int cbcol = bx * 64 + fr;
    const int Lm    = F_lens[mrow];            // for x-row reversal arithmetic
    int mm[4], LL[4], sidx[4];
    float c_own[4], h_own[4];
    float bias[4];
    const bf16_t* wihb[4];
#pragma unroll
    for (int j = 0; j < 4; ++j) {
        bias[j] = bp[d * G4 + cbcol + j * 16];
        wihb[j] = Wihp + ((size_t)d * G4 + bx * 64 + j * 16 + fr) * E_DIM + fq * 8;
    }
#pragma unroll
    for (int rr = 0; rr < 4; ++rr) {
        mm[rr]   = m0 + wave * 16 + fq * 4 + rr;
        LL[rr]   = F_lens[mm[rr]];
        sidx[rr] = (d * M_B + mm[rr]) * H_DIM + u;
        c_own[rr] = 0.f;
        h_own[rr] = 0.f;
    }

    // x-projection for step 0 into acc (no dependence on LDS staging).
    f32x4 acc[4];
#pragma unroll
    for (int j = 0; j < 4; ++j) { f32x4 z = {0.f, 0.f, 0.f, 0.f}; acc[j] = z; }
    {
        const int trx = (d == 0) ? 0 : (Lm - 1);
        const bf16_t* Xrow = Xin + ((size_t)trx * M_B + mrow) * E_DIM + fq * 8;
#pragma unroll
        for (int half = 0; half < 2; ++half) {
            bf16x8 ax[16];
#pragma unroll
            for (int ks = 0; ks < 16; ++ks)
                ax[ks] = *(const bf16x8*)(Xrow + half * 512 + ks * 32);
#pragma unroll
            for (int ks = 0; ks < 16; ++ks) {
#pragma unroll
                for (int j = 0; j < 4; ++j) {
                    bf16x8 bw = *(const bf16x8*)(wihb[j] + half * 512 + ks * 32);
                    acc[j] = __builtin_amdgcn_mfma_f32_16x16x32_bf16(ax[ks], bw, acc[j], 0, 0, 0);
                }
            }
        }
    }

    __syncthreads();   // Whh staging drained (compiler emits vmcnt0 before barrier)

    for (int tt = 0; tt < TC; ++tt) {
        const int t = tt;
        const bf16_t* hin  = (t & 1) ? hbB : hbA;
        bf16_t*       hout = (t & 1) ? hbA : hbB;

        // ---- critical path: h-part (skipped at t==0: h_prev = 0) ----
        if (t > 0) {
            const bf16_t* Arow = hin + ((size_t)d * M_B + mrow) * H_DIM + fq * 8;
            bf16x8 af[16];
#pragma unroll
            for (int ks = 0; ks < 16; ++ks)
                af[ks] = load_h_dev(Arow + ks * 32);
            asm volatile("s_waitcnt vmcnt(0)" ::: "memory");
            __builtin_amdgcn_sched_barrier(0);

#pragma unroll
            for (int ks = 0; ks < 16; ++ks) {
#pragma unroll
                for (int j = 0; j < 4; ++j) {
                    int rb = j * 16 + fr;
                    int ck = (ks * 4 + fq) ^ (rb & 7);
                    bf16x8 bf = *(const bf16x8*)&Bt[rb * 512 + ck * 8];
                    acc[j] = __builtin_amdgcn_mfma_f32_16x16x32_bf16(af[ks], bf, acc[j], 0, 0, 0);
                }
            }
        }

        // LSTM cell + h stores (critical path).
#pragma unroll
        for (int rr = 0; rr < 4; ++rr) {
            bool mt = (t < LL[rr]);
            float gi = acc[0][rr] + bias[0];
            float gf = acc[1][rr] + bias[1];
            float gg = acc[2][rr] + bias[2];
            float go = acc[3][rr] + bias[3];
            float c2 = sigm(gf) * c_own[rr] + sigm(gi) * tanhfast(gg);
            float h2 = sigm(go) * tanhfast(c2);
            if (!mt) { c2 = c_own[rr]; h2 = h_own[rr]; }
            c_own[rr] = c2;
            h_own[rr] = h2;
            store_h_dev(&hout[sidx[rr]], (bf16_t)h2);
        }
        asm volatile("s_waitcnt vmcnt(0)" ::: "memory");  // h stores device-visible
        __syncthreads();
        if (tid == 0)
            __hip_atomic_fetch_add(&ctr[gslot], 1u, __ATOMIC_RELAXED, __HIP_MEMORY_SCOPE_AGENT);

        // ---- shadow phase: output stores + x-projection for step t+1 ----
#pragma unroll
        for (int rr = 0; rr < 4; ++rr) {
            bool mt = (t < LL[rr]);
            int trow = (d == 0 || !mt) ? t : (LL[rr] - 1 - t);
            size_t orow = (size_t)trow * M_B + mm[rr];
            if (mode == 0) H1[orow * 1024 + d * H_DIM + u] = (bf16_t)h_own[rr];
            else           OUT[orow * 1024 + d * H_DIM + u] = mt ? h_own[rr] : 0.f;
        }

#pragma unroll
        for (int j = 0; j < 4; ++j) { f32x4 z = {0.f, 0.f, 0.f, 0.f}; acc[j] = z; }
        if (tt + 1 < TC) {
            const int tn  = t + 1;
            const int trx = (d == 0 || tn >= Lm) ? tn : (Lm - 1 - tn);
            const bf16_t* Xrow = Xin + ((size_t)trx * M_B + mrow) * E_DIM + fq * 8;
#pragma unroll
            for (int half = 0; half < 2; ++half) {
                bf16x8 ax[16];
#pragma unroll
                for (int ks = 0; ks < 16; ++ks)
                    ax[ks] = *(const bf16x8*)(Xrow + half * 512 + ks * 32);
#pragma unroll
                for (int ks = 0; ks < 16; ++ks) {
#pragma unroll
                    for (int j = 0; j < 4; ++j) {
                        bf16x8 bw = *(const bf16x8*)(wihb[j] + half * 512 + ks * 32);
                        acc[j] = __builtin_amdgcn_mfma_f32_16x16x32_bf16(ax[ks], bw, acc[j], 0, 0, 0);
                    }
                }
            }
        }

        if (tid == 0) {
            unsigned int tgt = (unsigned int)(s_base + tt + 1) * 32u;
            while (__hip_atomic_load(&ctr[gslot], __ATOMIC_RELAXED, __HIP_MEMORY_SCOPE_AGENT) < tgt)
                __builtin_amdgcn_s_sleep(2);
        }
        __syncthreads();
    }
}

// ---------------------------------------------------------------------------
extern "C" void kernel_launch(void* const* d_in, const int* in_sizes, int n_in,
                              void* d_out, int out_size, void* d_ws, size_t ws_size,
                              hipStream_t stream)
{
    const int*   F      = (const int*)d_in[0];
    const int*   F_lens = (const int*)d_in[1];
    const float* emb    = (const float*)d_in[2];
    const float* Wih0   = (const float*)d_in[3];
    const float* Whh0   = (const float*)d_in[4];
    const float* b0     = (const float*)d_in[5];
    const float* Wih1   = (const float*)d_in[6];
    const float* Whh1   = (const float*)d_in[7];
    const float* b1     = (const float*)d_in[8];
    float* OUT = (float*)d_out;

    // Workspace (~154 MiB), 256B-aligned blocks. No PRE buffer needed.
    char* p = (char*)d_ws;
    auto alloc = [&](size_t bytes) { char* q = p; p += (bytes + 255) & ~(size_t)255; return (void*)q; };
    bf16_t* X0    = (bf16_t*)alloc((size_t)N_ROWS * E_DIM * 2);   // 64 MiB
    bf16_t* H1    = (bf16_t*)alloc((size_t)N_ROWS * 1024 * 2);    // 64 MiB
    bf16_t* Wih0p = (bf16_t*)alloc((size_t)2 * G4 * E_DIM * 2);   // 8 MiB
    bf16_t* Whh0p = (bf16_t*)alloc((size_t)2 * G4 * H_DIM * 2);   // 4 MiB
    bf16_t* Wih1p = (bf16_t*)alloc((size_t)2 * G4 * E_DIM * 2);   // 8 MiB
    bf16_t* Whh1p = (bf16_t*)alloc((size_t)2 * G4 * H_DIM * 2);   // 4 MiB
    float*  b0p   = (float*)alloc((size_t)2 * G4 * 4);
    float*  b1p   = (float*)alloc((size_t)2 * G4 * 4);
    bf16_t* hbA   = (bf16_t*)alloc((size_t)2 * M_B * H_DIM * 2);
    bf16_t* hbB   = (bf16_t*)alloc((size_t)2 * M_B * H_DIM * 2);
    unsigned int* ctr = (unsigned int*)alloc(512);
    if (ws_size < (size_t)(p - (char*)d_ws)) return;

    hipMemsetAsync(ctr, 0, 512, stream);
    permute_all_kernel<<<dim3(2 * 2 * G4), 256, 0, stream>>>(
        Wih0, Whh0, b0, Wih1, Whh1, b1, Wih0p, Whh0p, Wih1p, Whh1p, b0p, b1p);
    embed_kernel<<<dim3(N_ROWS), 256, 0, stream>>>(F, emb, X0);

    lstm_layer_kernel<<<dim3(32, 4, 2), dim3(256), 0, stream>>>(
        Whh0p, Wih0p, b0p, X0, F_lens, hbA, hbB, H1, OUT, ctr, 0, 0);
    lstm_layer_kernel<<<dim3(32, 4, 2), dim3(256), 0, stream>>>(
        Whh1p, Wih1p, b1p, H1, F_lens, hbA, hbB, H1, OUT, ctr, 1, S_LEN);
}

// Round 12
// 2478.786 us; speedup vs baseline: 2.3226x; 2.3226x over previous
//
#include <hip/hip_runtime.h>
#include <hip/hip_bf16.h>

// Problem dims
#define S_LEN 128
#define M_B   256
#define E_DIM 1024
#define H_DIM 512
#define G4    2048          // 4*H
#define N_ROWS (S_LEN*M_B)  // 32768
#define KD    1024          // GEMM K for both layers (E = 2H = 1024)

typedef __bf16 bf16_t;
typedef __bf16 bf16x8 __attribute__((ext_vector_type(8)));
typedef float  f32x4  __attribute__((ext_vector_type(4)));
typedef int    i32x4  __attribute__((ext_vector_type(4)));

#define AS1(p) ((const __attribute__((address_space(1))) void*)(p))
#define AS3(p) ((__attribute__((address_space(3))) void*)(p))

__device__ __forceinline__ float sigm(float x)     { return 1.f / (1.f + __expf(-x)); }
__device__ __forceinline__ float tanhfast(float x) { return 2.f / (1.f + __expf(-2.f * x)) - 1.f; }

// Device-scope (LLC) h exchange: write-through stores, cache-bypassing loads.
__device__ __forceinline__ void store_h_dev(bf16_t* p, bf16_t v) {
    unsigned int w = (unsigned int)__builtin_bit_cast(unsigned short, v);
    asm volatile("global_store_short %0, %1, off sc0 sc1" :: "v"(p), "v"(w) : "memory");
}
__device__ __forceinline__ bf16x8 load_h_dev(const bf16_t* p) {
    i32x4 r;
    asm volatile("global_load_dwordx4 %0, %1, off sc0 sc1" : "=v"(r) : "v"(p) : "memory");
    return __builtin_bit_cast(bf16x8, r);
}
// Plain f32x4 load via asm: issues where written (not sunk to use point).
__device__ __forceinline__ f32x4 load_pv4(const float* p) {
    f32x4 r;
    asm volatile("global_load_dwordx4 %0, %1, off" : "=v"(r) : "v"(p) : "memory");
    return r;
}

// ---------------------------------------------------------------------------
// Weight permutation + bf16 conversion, BOTH layers in one launch.
// Gate permutation: j' = q*64 + gate*16 + u16  <->  j = gate*512 + (q*16+u16)
// ---------------------------------------------------------------------------
__global__ __launch_bounds__(256)
void permute_all_kernel(const float* __restrict__ Wih0, const float* __restrict__ Whh0,
                        const float* __restrict__ b0,
                        const float* __restrict__ Wih1, const float* __restrict__ Whh1,
                        const float* __restrict__ b1,
                        bf16_t* __restrict__ Wih0p, bf16_t* __restrict__ Whh0p,
                        bf16_t* __restrict__ Wih1p, bf16_t* __restrict__ Whh1p,
                        float* __restrict__ b0p, float* __restrict__ b1p)
{
    int bid = blockIdx.x;            // lay*4096 + d*2048 + jp
    int lay = bid >> 12;
    int d   = (bid >> 11) & 1;
    int jp  = bid & 2047;
    int q = jp >> 6, r = jp & 63;
    int gate = r >> 4, u16 = r & 15;
    int j = gate * H_DIM + q * 16 + u16;

    const float* Wih = lay ? Wih1 : Wih0;
    const float* Whh = lay ? Whh1 : Whh0;
    const float* b   = lay ? b1 : b0;
    bf16_t* Wihp = lay ? Wih1p : Wih0p;
    bf16_t* Whhp = lay ? Whh1p : Whh0p;
    float*  bp   = lay ? b1p : b0p;

    const float* s_ih = Wih + ((size_t)d * G4 + j) * E_DIM;
    bf16_t*      d_ih = Wihp + ((size_t)d * G4 + jp) * E_DIM;
    for (int e = threadIdx.x; e < E_DIM; e += 256) d_ih[e] = (bf16_t)s_ih[e];

    const float* s_hh = Whh + ((size_t)d * G4 + j) * H_DIM;
    bf16_t*      d_hh = Whhp + ((size_t)d * G4 + jp) * H_DIM;
    for (int k = threadIdx.x; k < H_DIM; k += 256) d_hh[k] = (bf16_t)s_hh[k];

    if (threadIdx.x == 0) bp[d * G4 + jp] = b[d * G4 + j];
}

// ---------------------------------------------------------------------------
// Embedding lookup -> bf16 X (32768 x 1024), with rowmap fused (tid 0).
// srcrow[t*256+m] = ((t < L) ? L-1-t : t) * 256 + m   (self-inverse gather)
// ---------------------------------------------------------------------------
__global__ __launch_bounds__(256)
void embed_kernel(const int* __restrict__ F, const float* __restrict__ emb,
                  const int* __restrict__ F_lens,
                  bf16_t* __restrict__ X, int* __restrict__ srcrow)
{
    int n   = blockIdx.x;            // t*256 + m
    int tok = F[n];
    const float4* src = (const float4*)(emb + (size_t)tok * E_DIM);
    bf16_t*       dst = X + (size_t)n * E_DIM;
    for (int i = threadIdx.x; i < E_DIM / 4; i += 256) {
        float4 v = src[i];
        dst[i * 4 + 0] = (bf16_t)v.x;
        dst[i * 4 + 1] = (bf16_t)v.y;
        dst[i * 4 + 2] = (bf16_t)v.z;
        dst[i * 4 + 3] = (bf16_t)v.w;
    }
    if (threadIdx.x == 0) {
        int t = n >> 8, m = n & 255;
        int L = F_lens[m];
        int st = (t < L) ? (L - 1 - t) : t;
        srcrow[n] = st * M_B + m;
    }
}

// ---------------------------------------------------------------------------
// Chunked input-projection GEMM, BK=64, XOR-swizzled LDS, XCD-chunked block
// swizzle. PRE output layout: [d][r][unit 512][gate 4] f32 — one float4 per
// (row, unit), bias folded in (vectorized consumer reads).
// ---------------------------------------------------------------------------
#define BM 128
#define BN 128
#define BKG 64

__global__ __launch_bounds__(256)
void gemm_pre_kernel(const bf16_t* __restrict__ A,    // (32768, 1024) bf16
                     const bf16_t* __restrict__ Wp,   // (2, 2048, 1024) bf16
                     const float* __restrict__ bp,    // (2, 2048)
                     const int* __restrict__ srcrow,  // (32768)
                     float* __restrict__ PREc,        // (2, TCR, 512, 4) f32
                     int rowbase, int TCR)
{
    // Bijective XCD-chunk swizzle (nwg % 8 == 0).
    const int nwg = gridDim.x;
    const int qx  = nwg >> 3;
    const int orig = blockIdx.x;
    const int wg   = (orig & 7) * qx + (orig >> 3);
    const int MT   = TCR / BM;
    const int n_t  = wg & 15;
    const int m_t  = (wg >> 4) % MT;
    const int d    = wg / (16 * MT);

    const int n0   = n_t * BN;
    const int mloc = m_t * BM;
    const int tid  = threadIdx.x;
    const int lane = tid & 63, wave = tid >> 6;
    const int wm = wave >> 1, wn = wave & 1;
    const int fr = lane & 15, fq = lane >> 4;

    __shared__ __attribute__((aligned(16))) bf16_t At[BM * BKG];   // 16 KiB
    __shared__ __attribute__((aligned(16))) bf16_t Bt[BN * BKG];   // 16 KiB

    // Staging: per thread 4 A-rows + 4 B-rows (rows rA + 32*it), fixed source
    // column-chunk co = swizzled by row (pre-swizzled source, linear dest).
    const int rA = tid >> 3;                           // 0..31
    const int co = (((tid & 7) ^ (rA & 7)) << 3);      // element offset in row
    size_t srowA[4];
    const bf16_t* Bp[4];
#pragma unroll
    for (int it = 0; it < 4; ++it) {
        int nn = rowbase + mloc + rA + it * 32;
        srowA[it] = (d == 1) ? (size_t)srcrow[nn] : (size_t)nn;
        Bp[it] = Wp + ((size_t)d * G4 + n0 + rA + it * 32) * KD + co;
    }

    f32x4 acc[4][4];
#pragma unroll
    for (int i = 0; i < 4; ++i)
#pragma unroll
        for (int j = 0; j < 4; ++j) { f32x4 z = {0.f, 0.f, 0.f, 0.f}; acc[i][j] = z; }

    for (int kt = 0; kt < KD; kt += BKG) {
#pragma unroll
        for (int it = 0; it < 4; ++it)
            __builtin_amdgcn_global_load_lds(AS1(A + srowA[it] * KD + kt + co),
                                             AS3(&At[(it * 256 + wave * 64) * 8]), 16, 0, 0);
#pragma unroll
        for (int it = 0; it < 4; ++it)
            __builtin_amdgcn_global_load_lds(AS1(Bp[it] + kt),
                                             AS3(&Bt[(it * 256 + wave * 64) * 8]), 16, 0, 0);
        __syncthreads();

        bf16x8 af[2][4], bff[2][4];
#pragma unroll
        for (int ks = 0; ks < 2; ++ks) {
#pragma unroll
            for (int i = 0; i < 4; ++i) {
                int ra = wm * 64 + i * 16 + fr;
                int ca = (ks * 4 + fq) ^ (ra & 7);
                af[ks][i] = *(const bf16x8*)&At[ra * BKG + ca * 8];
                int rb = wn * 64 + i * 16 + fr;
                int cbk = (ks * 4 + fq) ^ (rb & 7);
                bff[ks][i] = *(const bf16x8*)&Bt[rb * BKG + cbk * 8];
            }
        }
#pragma unroll
        for (int ks = 0; ks < 2; ++ks)
#pragma unroll
            for (int i = 0; i < 4; ++i)
#pragma unroll
                for (int j = 0; j < 4; ++j)
                    acc[i][j] = __builtin_amdgcn_mfma_f32_16x16x32_bf16(af[ks][i], bff[ks][j], acc[i][j], 0, 0, 0);
        __syncthreads();
    }

    // Epilogue: gate-interleaved float4 store. unit = ((n0>>6)+wn)*16 + fr,
    // gate g = old col n0+wn*64+fr+g*16 (bias folded here).
    const int ucol = ((n0 >> 6) + wn) * 16 + fr;
    float bq[4];
#pragma unroll
    for (int g = 0; g < 4; ++g) bq[g] = bp[d * G4 + n0 + wn * 64 + fr + g * 16];
#pragma unroll
    for (int mi = 0; mi < 4; ++mi) {
#pragma unroll
        for (int rr = 0; rr < 4; ++rr) {
            int r = mloc + wm * 64 + mi * 16 + fq * 4 + rr;
            f32x4 v;
#pragma unroll
            for (int g = 0; g < 4; ++g) v[g] = acc[mi][g][rr] + bq[g];
            *(f32x4*)&PREc[(((size_t)d * TCR + r) * 512 + ucol) * 4] = v;
        }
    }
}

// ---------------------------------------------------------------------------
// Persistent recurrence kernel, per-group barriers (R6/R8 structure).
// Grid (32,4,2)=256 blocks, 64KiB LDS. Groups: (my,d) -> 8 groups x 32 blocks.
// PRE read as ONE float4 per (row, unit) — vectorized, issued in the shadow
// phase so HBM latency hides under the barrier poll.
// ---------------------------------------------------------------------------
__global__ __launch_bounds__(256)
void lstm_chunk_kernel(const bf16_t* __restrict__ Whhp,  // (2,2048,512) bf16
                       const float* __restrict__ PREc,   // (2,TCR,512,4) f32
                       const int* __restrict__ F_lens,
                       float* __restrict__ cfb,          // (2,256,512) f32
                       bf16_t* __restrict__ hbA,         // (2,256,512) bf16
                       bf16_t* __restrict__ hbB,         // (2,256,512) bf16
                       bf16_t* __restrict__ H1,          // (32768,1024) bf16 (mode 0)
                       float* __restrict__ OUT,          // (32768,1024) f32  (mode 1)
                       unsigned int* __restrict__ ctr,   // 8 group counters, 64B apart
                       int t0, int TC, int TCR, int mode, int s_base)
{
    const int d  = blockIdx.z;
    const int bx = blockIdx.x;          // unit group 0..31
    const int m0 = blockIdx.y * 64;
    const int tid = threadIdx.x;
    const int lane = tid & 63, wave = tid >> 6;
    const int fr = lane & 15, fq = lane >> 4;
    const int gslot = ((blockIdx.y << 1) | d) * 16;   // 64B-spaced counter

    __shared__ __attribute__((aligned(16))) bf16_t Bt[64 * 512];   // 64 KiB

    // Stage Whh slice (64 rows x 512 K) once; XOR-swizzled SOURCE, linear dest.
    const bf16_t* Bg = Whhp + ((size_t)d * G4 + bx * 64) * H_DIM;
#pragma unroll
    for (int it = 0; it < 16; ++it) {
        int c   = it * 256 + tid;
        int row = c >> 6, ck = c & 63;
        int cks = ck ^ (row & 7);
        __builtin_amdgcn_global_load_lds(AS1(Bg + (size_t)row * H_DIM + cks * 8),
                                         AS3(&Bt[(it * 256 + wave * 64) * 8]), 16, 0, 0);
    }

    // Per-lane constants (lane owns unit u for 4 fixed m-rows, all steps).
    const int mrow  = m0 + wave * 16 + fr;     // A-fragment row
    const int u     = bx * 16 + fr;
    int mm[4], LL[4], sidx[4];
    float c_own[4], h_own[4];
    const float* pbase[4];
#pragma unroll
    for (int rr = 0; rr < 4; ++rr) {
        mm[rr]   = m0 + wave * 16 + fq * 4 + rr;
        LL[rr]   = F_lens[mm[rr]];
        sidx[rr] = (d * M_B + mm[rr]) * H_DIM + u;
        c_own[rr]= cfb[sidx[rr]];
        pbase[rr]= PREc + (((size_t)d * TCR + mm[rr]) * 512 + u) * 4;
    }
    {
        const bf16_t* hin0 = (t0 & 1) ? hbB : hbA;
#pragma unroll
        for (int rr = 0; rr < 4; ++rr) h_own[rr] = (float)hin0[sidx[rr]];
    }

    // pv for step 0 (one float4 per rr).
    f32x4 pv[4];
#pragma unroll
    for (int rr = 0; rr < 4; ++rr)
        pv[rr] = load_pv4(pbase[rr]);

    __syncthreads();   // staging + pv drained (compiler emits vmcnt0 before barrier)

    for (int tt = 0; tt < TC; ++tt) {
        const int t = t0 + tt;
        const bf16_t* hin  = (t & 1) ? hbB : hbA;
        bf16_t*       hout = (t & 1) ? hbA : hbB;

        // h fragments (device-scope, bypass L1/L2 -> LLC where producers wrote).
        const bf16_t* Arow = hin + ((size_t)d * M_B + mrow) * H_DIM + fq * 8;
        bf16x8 af[16];
#pragma unroll
        for (int ks = 0; ks < 16; ++ks)
            af[ks] = load_h_dev(Arow + ks * 32);
        asm volatile("s_waitcnt vmcnt(0)" ::: "memory");
        __builtin_amdgcn_sched_barrier(0);

        f32x4 acc[4];
#pragma unroll
        for (int j = 0; j < 4; ++j) { f32x4 z = {0.f, 0.f, 0.f, 0.f}; acc[j] = z; }

#pragma unroll
        for (int ks = 0; ks < 16; ++ks) {
#pragma unroll
            for (int j = 0; j < 4; ++j) {
                int rb = j * 16 + fr;
                int ck = (ks * 4 + fq) ^ (rb & 7);
                bf16x8 bf = *(const bf16x8*)&Bt[rb * 512 + ck * 8];
                acc[j] = __builtin_amdgcn_mfma_f32_16x16x32_bf16(af[ks], bf, acc[j], 0, 0, 0);
            }
        }

        // LSTM cell + h stores (critical path).
#pragma unroll
        for (int rr = 0; rr < 4; ++rr) {
            bool mt = (t < LL[rr]);
            float gi = acc[0][rr] + pv[rr][0];
            float gf = acc[1][rr] + pv[rr][1];
            float gg = acc[2][rr] + pv[rr][2];
            float go = acc[3][rr] + pv[rr][3];
            float c2 = sigm(gf) * c_own[rr] + sigm(gi) * tanhfast(gg);
            float h2 = sigm(go) * tanhfast(c2);
            if (!mt) { c2 = c_own[rr]; h2 = h_own[rr]; }
            c_own[rr] = c2;
            h_own[rr] = h2;
            store_h_dev(&hout[sidx[rr]], (bf16_t)h2);
        }
        asm volatile("s_waitcnt vmcnt(0)" ::: "memory");  // h stores device-visible
        __syncthreads();
        if (tid == 0)
            __hip_atomic_fetch_add(&ctr[gslot], 1u, __ATOMIC_RELAXED, __HIP_MEMORY_SCOPE_AGENT);

        // Off-critical-path: output stores + next-step PRE prefetch (overlap poll).
#pragma unroll
        for (int rr = 0; rr < 4; ++rr) {
            bool mt = (t < LL[rr]);
            int trow = (d == 0 || !mt) ? t : (LL[rr] - 1 - t);
            size_t orow = (size_t)trow * M_B + mm[rr];
            if (mode == 0) H1[orow * 1024 + d * H_DIM + u] = (bf16_t)h_own[rr];
            else           OUT[orow * 1024 + d * H_DIM + u] = mt ? h_own[rr] : 0.f;
        }
        f32x4 pvn[4];
        if (tt + 1 < TC) {
#pragma unroll
            for (int rr = 0; rr < 4; ++rr)
                pvn[rr] = load_pv4(pbase[rr] + (size_t)(tt + 1) * ((size_t)M_B * G4));
        }

        if (tid == 0) {
            unsigned int tgt = (unsigned int)(s_base + tt + 1) * 32u;
            while (__hip_atomic_load(&ctr[gslot], __ATOMIC_RELAXED, __HIP_MEMORY_SCOPE_AGENT) < tgt)
                __builtin_amdgcn_s_sleep(2);
        }
        __syncthreads();

        if (tt + 1 < TC) {
#pragma unroll
            for (int rr = 0; rr < 4; ++rr)
                pv[rr] = pvn[rr];
        }
    }

#pragma unroll
    for (int rr = 0; rr < 4; ++rr) cfb[sidx[rr]] = c_own[rr];
}

// ---------------------------------------------------------------------------
extern "C" void kernel_launch(void* const* d_in, const int* in_sizes, int n_in,
                              void* d_out, int out_size, void* d_ws, size_t ws_size,
                              hipStream_t stream)
{
    const int*   F      = (const int*)d_in[0];
    const int*   F_lens = (const int*)d_in[1];
    const float* emb    = (const float*)d_in[2];
    const float* Wih0   = (const float*)d_in[3];
    const float* Whh0   = (const float*)d_in[4];
    const float* b0     = (const float*)d_in[5];
    const float* Wih1   = (const float*)d_in[6];
    const float* Whh1   = (const float*)d_in[7];
    const float* b1     = (const float*)d_in[8];
    float* OUT = (float*)d_out;

    // Base workspace (~155 MiB), 256B-aligned blocks.
    char* p = (char*)d_ws;
    auto alloc = [&](size_t bytes) { char* q = p; p += (bytes + 255) & ~(size_t)255; return (void*)q; };
    bf16_t* X0    = (bf16_t*)alloc((size_t)N_ROWS * E_DIM * 2);   // 64 MiB
    bf16_t* H1    = (bf16_t*)alloc((size_t)N_ROWS * 1024 * 2);    // 64 MiB
    bf16_t* Wih0p = (bf16_t*)alloc((size_t)2 * G4 * E_DIM * 2);   // 8 MiB
    bf16_t* Whh0p = (bf16_t*)alloc((size_t)2 * G4 * H_DIM * 2);   // 4 MiB
    bf16_t* Wih1p = (bf16_t*)alloc((size_t)2 * G4 * E_DIM * 2);   // 8 MiB
    bf16_t* Whh1p = (bf16_t*)alloc((size_t)2 * G4 * H_DIM * 2);   // 4 MiB
    float*  b0p   = (float*)alloc((size_t)2 * G4 * 4);
    float*  b1p   = (float*)alloc((size_t)2 * G4 * 4);
    int*    srcrow= (int*)alloc((size_t)N_ROWS * 4);              // 128 KiB
    bf16_t* hbA   = (bf16_t*)alloc((size_t)2 * M_B * H_DIM * 2);
    bf16_t* hbB   = (bf16_t*)alloc((size_t)2 * M_B * H_DIM * 2);
    float*  cfb   = (float*)alloc((size_t)2 * M_B * H_DIM * 4);
    unsigned int* ctr = (unsigned int*)alloc(512);
    size_t base_used = (size_t)(p - (char*)d_ws);

    // Largest time-chunk whose f32 PRE buffer fits the remaining workspace.
    int TC = 0;
    const int tcs[8] = {128, 64, 32, 16, 8, 4, 2, 1};
    for (int i = 0; i < 8; ++i) {
        size_t need = base_used + (size_t)2 * tcs[i] * M_B * G4 * 4;
        if (need <= ws_size) { TC = tcs[i]; break; }
    }
    if (TC == 0) return;  // cannot run at all
    float* PREc = (float*)p;
    const int TCR = TC * M_B;

    hipMemsetAsync(ctr, 0, 512, stream);
    permute_all_kernel<<<dim3(2 * 2 * G4), 256, 0, stream>>>(
        Wih0, Whh0, b0, Wih1, Whh1, b1, Wih0p, Whh0p, Wih1p, Whh1p, b0p, b1p);
    embed_kernel<<<dim3(N_ROWS), 256, 0, stream>>>(F, emb, F_lens, X0, srcrow);

    for (int layer = 0; layer < 2; ++layer) {
        const bf16_t* Xin  = layer ? H1 : X0;
        const bf16_t* Wihp = layer ? Wih1p : Wih0p;
        const bf16_t* Whhp = layer ? Whh1p : Whh0p;
        const float*  bp   = layer ? b1p : b0p;

        hipMemsetAsync(hbA, 0, (size_t)2 * M_B * H_DIM * 2, stream);
        hipMemsetAsync(cfb, 0, (size_t)2 * M_B * H_DIM * 4, stream);

        for (int c = 0; c < S_LEN / TC; ++c) {
            gemm_pre_kernel<<<dim3(2 * (TCR / BM) * 16), 256, 0, stream>>>(
                Xin, Wihp, bp, srcrow, PREc, c * TCR, TCR);

            lstm_chunk_kernel<<<dim3(32, 4, 2), dim3(256), 0, stream>>>(
                Whhp, PREc, F_lens, cfb, hbA, hbB, H1, OUT, ctr,
                c * TC, TC, TCR, layer, layer * S_LEN + c * TC);
        }
    }
}

// Round 13
// 2401.105 us; speedup vs baseline: 2.3978x; 1.0324x over previous
//
#include <hip/hip_runtime.h>
#include <hip/hip_bf16.h>

// Problem dims
#define S_LEN 128
#define M_B   256
#define E_DIM 1024
#define H_DIM 512
#define G4    2048          // 4*H
#define N_ROWS (S_LEN*M_B)  // 32768
#define KD    1024          // GEMM K for both layers (E = 2H = 1024)

typedef __bf16 bf16_t;
typedef __bf16 bf16x8 __attribute__((ext_vector_type(8)));
typedef float  f32x4  __attribute__((ext_vector_type(4)));
typedef int    i32x4  __attribute__((ext_vector_type(4)));

#define AS1(p) ((const __attribute__((address_space(1))) void*)(p))
#define AS3(p) ((__attribute__((address_space(3))) void*)(p))

__device__ __forceinline__ float sigm(float x)     { return 1.f / (1.f + __expf(-x)); }
__device__ __forceinline__ float tanhfast(float x) { return 2.f / (1.f + __expf(-2.f * x)) - 1.f; }

// Device-scope (LLC) h exchange: write-through stores, cache-bypassing loads.
__device__ __forceinline__ void store_h_dev(bf16_t* p, bf16_t v) {
    unsigned int w = (unsigned int)__builtin_bit_cast(unsigned short, v);
    asm volatile("global_store_short %0, %1, off sc0 sc1" :: "v"(p), "v"(w) : "memory");
}
__device__ __forceinline__ bf16x8 load_h_dev(const bf16_t* p) {
    i32x4 r;
    asm volatile("global_load_dwordx4 %0, %1, off sc0 sc1" : "=v"(r) : "v"(p) : "memory");
    return __builtin_bit_cast(bf16x8, r);
}
// Plain f32x4 load via asm: issues where written (not sunk to use point).
__device__ __forceinline__ f32x4 load_pv4(const float* p) {
    f32x4 r;
    asm volatile("global_load_dwordx4 %0, %1, off" : "=v"(r) : "v"(p) : "memory");
    return r;
}
// Flag barrier primitives (plain stores/loads, LLC-coherent, no RMW).
__device__ __forceinline__ void store_flag(unsigned int* p, unsigned int v) {
    asm volatile("global_store_dword %0, %1, off sc0 sc1" :: "v"(p), "v"(v) : "memory");
}
__device__ __forceinline__ unsigned int load_flag(const unsigned int* p) {
    unsigned int r;
    asm volatile("global_load_dword %0, %1, off sc0 sc1\n\ts_waitcnt vmcnt(0)"
                 : "=v"(r) : "v"(p) : "memory");
    return r;
}

// ---------------------------------------------------------------------------
// Weight permutation + bf16 conversion, BOTH layers in one launch.
// Gate permutation: j' = q*64 + gate*16 + u16  <->  j = gate*512 + (q*16+u16)
// ---------------------------------------------------------------------------
__global__ __launch_bounds__(256)
void permute_all_kernel(const float* __restrict__ Wih0, const float* __restrict__ Whh0,
                        const float* __restrict__ b0,
                        const float* __restrict__ Wih1, const float* __restrict__ Whh1,
                        const float* __restrict__ b1,
                        bf16_t* __restrict__ Wih0p, bf16_t* __restrict__ Whh0p,
                        bf16_t* __restrict__ Wih1p, bf16_t* __restrict__ Whh1p,
                        float* __restrict__ b0p, float* __restrict__ b1p)
{
    int bid = blockIdx.x;            // lay*4096 + d*2048 + jp
    int lay = bid >> 12;
    int d   = (bid >> 11) & 1;
    int jp  = bid & 2047;
    int q = jp >> 6, r = jp & 63;
    int gate = r >> 4, u16 = r & 15;
    int j = gate * H_DIM + q * 16 + u16;

    const float* Wih = lay ? Wih1 : Wih0;
    const float* Whh = lay ? Whh1 : Whh0;
    const float* b   = lay ? b1 : b0;
    bf16_t* Wihp = lay ? Wih1p : Wih0p;
    bf16_t* Whhp = lay ? Whh1p : Whh0p;
    float*  bp   = lay ? b1p : b0p;

    const float* s_ih = Wih + ((size_t)d * G4 + j) * E_DIM;
    bf16_t*      d_ih = Wihp + ((size_t)d * G4 + jp) * E_DIM;
    for (int e = threadIdx.x; e < E_DIM; e += 256) d_ih[e] = (bf16_t)s_ih[e];

    const float* s_hh = Whh + ((size_t)d * G4 + j) * H_DIM;
    bf16_t*      d_hh = Whhp + ((size_t)d * G4 + jp) * H_DIM;
    for (int k = threadIdx.x; k < H_DIM; k += 256) d_hh[k] = (bf16_t)s_hh[k];

    if (threadIdx.x == 0) bp[d * G4 + jp] = b[d * G4 + j];
}

// ---------------------------------------------------------------------------
// Embedding lookup -> bf16 X (32768 x 1024), with rowmap fused (tid 0).
// srcrow[t*256+m] = ((t < L) ? L-1-t : t) * 256 + m   (self-inverse gather)
// ---------------------------------------------------------------------------
__global__ __launch_bounds__(256)
void embed_kernel(const int* __restrict__ F, const float* __restrict__ emb,
                  const int* __restrict__ F_lens,
                  bf16_t* __restrict__ X, int* __restrict__ srcrow)
{
    int n   = blockIdx.x;            // t*256 + m
    int tok = F[n];
    const float4* src = (const float4*)(emb + (size_t)tok * E_DIM);
    bf16_t*       dst = X + (size_t)n * E_DIM;
    for (int i = threadIdx.x; i < E_DIM / 4; i += 256) {
        float4 v = src[i];
        dst[i * 4 + 0] = (bf16_t)v.x;
        dst[i * 4 + 1] = (bf16_t)v.y;
        dst[i * 4 + 2] = (bf16_t)v.z;
        dst[i * 4 + 3] = (bf16_t)v.w;
    }
    if (threadIdx.x == 0) {
        int t = n >> 8, m = n & 255;
        int L = F_lens[m];
        int st = (t < L) ? (L - 1 - t) : t;
        srcrow[n] = st * M_B + m;
    }
}

// ---------------------------------------------------------------------------
// Chunked input-projection GEMM, BK=64, XOR-swizzled LDS, XCD-chunked block
// swizzle. PRE output layout: [d][r][unit 512][gate 4] f32 — one float4 per
// (row, unit), bias folded in (vectorized consumer reads).
// ---------------------------------------------------------------------------
#define BM 128
#define BN 128
#define BKG 64

__global__ __launch_bounds__(256)
void gemm_pre_kernel(const bf16_t* __restrict__ A,    // (32768, 1024) bf16
                     const bf16_t* __restrict__ Wp,   // (2, 2048, 1024) bf16
                     const float* __restrict__ bp,    // (2, 2048)
                     const int* __restrict__ srcrow,  // (32768)
                     float* __restrict__ PREc,        // (2, TCR, 512, 4) f32
                     int rowbase, int TCR)
{
    // Bijective XCD-chunk swizzle (nwg % 8 == 0).
    const int nwg = gridDim.x;
    const int qx  = nwg >> 3;
    const int orig = blockIdx.x;
    const int wg   = (orig & 7) * qx + (orig >> 3);
    const int MT   = TCR / BM;
    const int n_t  = wg & 15;
    const int m_t  = (wg >> 4) % MT;
    const int d    = wg / (16 * MT);

    const int n0   = n_t * BN;
    const int mloc = m_t * BM;
    const int tid  = threadIdx.x;
    const int lane = tid & 63, wave = tid >> 6;
    const int wm = wave >> 1, wn = wave & 1;
    const int fr = lane & 15, fq = lane >> 4;

    __shared__ __attribute__((aligned(16))) bf16_t At[BM * BKG];   // 16 KiB
    __shared__ __attribute__((aligned(16))) bf16_t Bt[BN * BKG];   // 16 KiB

    // Staging: per thread 4 A-rows + 4 B-rows (rows rA + 32*it), fixed source
    // column-chunk co = swizzled by row (pre-swizzled source, linear dest).
    const int rA = tid >> 3;                           // 0..31
    const int co = (((tid & 7) ^ (rA & 7)) << 3);      // element offset in row
    size_t srowA[4];
    const bf16_t* Bp[4];
#pragma unroll
    for (int it = 0; it < 4; ++it) {
        int nn = rowbase + mloc + rA + it * 32;
        srowA[it] = (d == 1) ? (size_t)srcrow[nn] : (size_t)nn;
        Bp[it] = Wp + ((size_t)d * G4 + n0 + rA + it * 32) * KD + co;
    }

    f32x4 acc[4][4];
#pragma unroll
    for (int i = 0; i < 4; ++i)
#pragma unroll
        for (int j = 0; j < 4; ++j) { f32x4 z = {0.f, 0.f, 0.f, 0.f}; acc[i][j] = z; }

    for (int kt = 0; kt < KD; kt += BKG) {
#pragma unroll
        for (int it = 0; it < 4; ++it)
            __builtin_amdgcn_global_load_lds(AS1(A + srowA[it] * KD + kt + co),
                                             AS3(&At[(it * 256 + wave * 64) * 8]), 16, 0, 0);
#pragma unroll
        for (int it = 0; it < 4; ++it)
            __builtin_amdgcn_global_load_lds(AS1(Bp[it] + kt),
                                             AS3(&Bt[(it * 256 + wave * 64) * 8]), 16, 0, 0);
        __syncthreads();

        bf16x8 af[2][4], bff[2][4];
#pragma unroll
        for (int ks = 0; ks < 2; ++ks) {
#pragma unroll
            for (int i = 0; i < 4; ++i) {
                int ra = wm * 64 + i * 16 + fr;
                int ca = (ks * 4 + fq) ^ (ra & 7);
                af[ks][i] = *(const bf16x8*)&At[ra * BKG + ca * 8];
                int rb = wn * 64 + i * 16 + fr;
                int cbk = (ks * 4 + fq) ^ (rb & 7);
                bff[ks][i] = *(const bf16x8*)&Bt[rb * BKG + cbk * 8];
            }
        }
#pragma unroll
        for (int ks = 0; ks < 2; ++ks)
#pragma unroll
            for (int i = 0; i < 4; ++i)
#pragma unroll
                for (int j = 0; j < 4; ++j)
                    acc[i][j] = __builtin_amdgcn_mfma_f32_16x16x32_bf16(af[ks][i], bff[ks][j], acc[i][j], 0, 0, 0);
        __syncthreads();
    }

    // Epilogue: gate-interleaved float4 store. unit = ((n0>>6)+wn)*16 + fr,
    // gate g = old col n0+wn*64+fr+g*16 (bias folded here).
    const int ucol = ((n0 >> 6) + wn) * 16 + fr;
    float bq[4];
#pragma unroll
    for (int g = 0; g < 4; ++g) bq[g] = bp[d * G4 + n0 + wn * 64 + fr + g * 16];
#pragma unroll
    for (int mi = 0; mi < 4; ++mi) {
#pragma unroll
        for (int rr = 0; rr < 4; ++rr) {
            int r = mloc + wm * 64 + mi * 16 + fq * 4 + rr;
            f32x4 v;
#pragma unroll
            for (int g = 0; g < 4; ++g) v[g] = acc[mi][g][rr] + bq[g];
            *(f32x4*)&PREc[(((size_t)d * TCR + r) * 512 + ucol) * 4] = v;
        }
    }
}

// ---------------------------------------------------------------------------
// Persistent recurrence kernel with WAVE-GRANULAR FLAG BARRIER.
// Rings: (my, d, wave) -> 32 rings of 32 waves. Wave w of any block touches
// ONLY h rows [m0+16w, m0+16w+16) for both loads and stores, so rings are
// fully independent; no per-step __syncthreads needed (Bt is read-only after
// init; all other state is lane-private). Flags are plain sc0sc1 dword
// stores (no atomic RMW serialization); each ring owns a private 128B line.
// ---------------------------------------------------------------------------
__global__ __launch_bounds__(256)
void lstm_chunk_kernel(const bf16_t* __restrict__ Whhp,  // (2,2048,512) bf16
                       const float* __restrict__ PREc,   // (2,TCR,512,4) f32
                       const int* __restrict__ F_lens,
                       float* __restrict__ cfb,          // (2,256,512) f32
                       bf16_t* __restrict__ hbA,         // (2,256,512) bf16
                       bf16_t* __restrict__ hbB,         // (2,256,512) bf16
                       bf16_t* __restrict__ H1,          // (32768,1024) bf16 (mode 0)
                       float* __restrict__ OUT,          // (32768,1024) f32  (mode 1)
                       unsigned int* __restrict__ flags, // 32 rings x 32 x u32 (128B/ring)
                       int t0, int TC, int TCR, int mode, int s_base)
{
    const int d  = blockIdx.z;
    const int bx = blockIdx.x;          // unit group 0..31
    const int m0 = blockIdx.y * 64;
    const int tid = threadIdx.x;
    const int lane = tid & 63, wave = tid >> 6;
    const int fr = lane & 15, fq = lane >> 4;
    // Ring = (my, d, wave); private 128B flag line per ring.
    unsigned int* gflags = flags + ((((blockIdx.y << 1) | d) << 2) + wave) * 32;

    __shared__ __attribute__((aligned(16))) bf16_t Bt[64 * 512];   // 64 KiB

    // Stage Whh slice (64 rows x 512 K) once; XOR-swizzled SOURCE, linear dest.
    const bf16_t* Bg = Whhp + ((size_t)d * G4 + bx * 64) * H_DIM;
#pragma unroll
    for (int it = 0; it < 16; ++it) {
        int c   = it * 256 + tid;
        int row = c >> 6, ck = c & 63;
        int cks = ck ^ (row & 7);
        __builtin_amdgcn_global_load_lds(AS1(Bg + (size_t)row * H_DIM + cks * 8),
                                         AS3(&Bt[(it * 256 + wave * 64) * 8]), 16, 0, 0);
    }

    // Per-lane constants (lane owns unit u for 4 fixed m-rows, all steps).
    const int mrow  = m0 + wave * 16 + fr;     // A-fragment row
    const int u     = bx * 16 + fr;
    int mm[4], LL[4], sidx[4];
    float c_own[4], h_own[4];
    const float* pbase[4];
#pragma unroll
    for (int rr = 0; rr < 4; ++rr) {
        mm[rr]   = m0 + wave * 16 + fq * 4 + rr;
        LL[rr]   = F_lens[mm[rr]];
        sidx[rr] = (d * M_B + mm[rr]) * H_DIM + u;
        c_own[rr]= cfb[sidx[rr]];
        pbase[rr]= PREc + (((size_t)d * TCR + mm[rr]) * 512 + u) * 4;
    }
    {
        const bf16_t* hin0 = (t0 & 1) ? hbB : hbA;
#pragma unroll
        for (int rr = 0; rr < 4; ++rr) h_own[rr] = (float)hin0[sidx[rr]];
    }

    // pv for step 0 (one float4 per rr).
    f32x4 pv[4];
#pragma unroll
    for (int rr = 0; rr < 4; ++rr)
        pv[rr] = load_pv4(pbase[rr]);

    __syncthreads();   // Whh staging drained (compiler emits vmcnt0 before barrier)

    for (int tt = 0; tt < TC; ++tt) {
        const int t = t0 + tt;
        const bf16_t* hin  = (t & 1) ? hbB : hbA;
        bf16_t*       hout = (t & 1) ? hbA : hbB;

        // h fragments (device-scope, bypass L1/L2 -> LLC where producers wrote).
        const bf16_t* Arow = hin + ((size_t)d * M_B + mrow) * H_DIM + fq * 8;
        bf16x8 af[16];
#pragma unroll
        for (int ks = 0; ks < 16; ++ks)
            af[ks] = load_h_dev(Arow + ks * 32);
        asm volatile("s_waitcnt vmcnt(0)" ::: "memory");
        __builtin_amdgcn_sched_barrier(0);

        f32x4 acc[4];
#pragma unroll
        for (int j = 0; j < 4; ++j) { f32x4 z = {0.f, 0.f, 0.f, 0.f}; acc[j] = z; }

#pragma unroll
        for (int ks = 0; ks < 16; ++ks) {
#pragma unroll
            for (int j = 0; j < 4; ++j) {
                int rb = j * 16 + fr;
                int ck = (ks * 4 + fq) ^ (rb & 7);
                bf16x8 bf = *(const bf16x8*)&Bt[rb * 512 + ck * 8];
                acc[j] = __builtin_amdgcn_mfma_f32_16x16x32_bf16(af[ks], bf, acc[j], 0, 0, 0);
            }
        }

        // LSTM cell + h stores (critical path).
#pragma unroll
        for (int rr = 0; rr < 4; ++rr) {
            bool mt = (t < LL[rr]);
            float gi = acc[0][rr] + pv[rr][0];
            float gf = acc[1][rr] + pv[rr][1];
            float gg = acc[2][rr] + pv[rr][2];
            float go = acc[3][rr] + pv[rr][3];
            float c2 = sigm(gf) * c_own[rr] + sigm(gi) * tanhfast(gg);
            float h2 = sigm(go) * tanhfast(c2);
            if (!mt) { c2 = c_own[rr]; h2 = h_own[rr]; }
            c_own[rr] = c2;
            h_own[rr] = h2;
            store_h_dev(&hout[sidx[rr]], (bf16_t)h2);
        }
        asm volatile("s_waitcnt vmcnt(0)" ::: "memory");  // this wave's h stores visible
        if (lane == 0)
            store_flag(&gflags[bx], (unsigned int)(s_base + tt + 1));

        // Off-critical-path: output stores + next-step PRE prefetch (overlap poll).
#pragma unroll
        for (int rr = 0; rr < 4; ++rr) {
            bool mt = (t < LL[rr]);
            int trow = (d == 0 || !mt) ? t : (LL[rr] - 1 - t);
            size_t orow = (size_t)trow * M_B + mm[rr];
            if (mode == 0) H1[orow * 1024 + d * H_DIM + u] = (bf16_t)h_own[rr];
            else           OUT[orow * 1024 + d * H_DIM + u] = mt ? h_own[rr] : 0.f;
        }
        f32x4 pvn[4];
        if (tt + 1 < TC) {
#pragma unroll
            for (int rr = 0; rr < 4; ++rr)
                pvn[rr] = load_pv4(pbase[rr] + (size_t)(tt + 1) * ((size_t)M_B * G4));
        }

        // Wave-granular flag poll: all 32 ring members at step >= t+1.
        {
            const unsigned int tgt = (unsigned int)(s_base + tt + 1);
            const unsigned int* fp = &gflags[lane & 31];
            while (__ballot(load_flag(fp) >= tgt) != ~0ull)
                __builtin_amdgcn_s_sleep(1);
        }

        if (tt + 1 < TC) {
#pragma unroll
            for (int rr = 0; rr < 4; ++rr)
                pv[rr] = pvn[rr];
        }
    }

#pragma unroll
    for (int rr = 0; rr < 4; ++rr) cfb[sidx[rr]] = c_own[rr];
}

// ---------------------------------------------------------------------------
extern "C" void kernel_launch(void* const* d_in, const int* in_sizes, int n_in,
                              void* d_out, int out_size, void* d_ws, size_t ws_size,
                              hipStream_t stream)
{
    const int*   F      = (const int*)d_in[0];
    const int*   F_lens = (const int*)d_in[1];
    const float* emb    = (const float*)d_in[2];
    const float* Wih0   = (const float*)d_in[3];
    const float* Whh0   = (const float*)d_in[4];
    const float* b0     = (const float*)d_in[5];
    const float* Wih1   = (const float*)d_in[6];
    const float* Whh1   = (const float*)d_in[7];
    const float* b1     = (const float*)d_in[8];
    float* OUT = (float*)d_out;

    // Base workspace (~155 MiB), 256B-aligned blocks.
    char* p = (char*)d_ws;
    auto alloc = [&](size_t bytes) { char* q = p; p += (bytes + 255) & ~(size_t)255; return (void*)q; };
    bf16_t* X0    = (bf16_t*)alloc((size_t)N_ROWS * E_DIM * 2);   // 64 MiB
    bf16_t* H1    = (bf16_t*)alloc((size_t)N_ROWS * 1024 * 2);    // 64 MiB
    bf16_t* Wih0p = (bf16_t*)alloc((size_t)2 * G4 * E_DIM * 2);   // 8 MiB
    bf16_t* Whh0p = (bf16_t*)alloc((size_t)2 * G4 * H_DIM * 2);   // 4 MiB
    bf16_t* Wih1p = (bf16_t*)alloc((size_t)2 * G4 * E_DIM * 2);   // 8 MiB
    bf16_t* Whh1p = (bf16_t*)alloc((size_t)2 * G4 * H_DIM * 2);   // 4 MiB
    float*  b0p   = (float*)alloc((size_t)2 * G4 * 4);
    float*  b1p   = (float*)alloc((size_t)2 * G4 * 4);
    int*    srcrow= (int*)alloc((size_t)N_ROWS * 4);              // 128 KiB
    bf16_t* hbA   = (bf16_t*)alloc((size_t)2 * M_B * H_DIM * 2);
    bf16_t* hbB   = (bf16_t*)alloc((size_t)2 * M_B * H_DIM * 2);
    float*  cfb   = (float*)alloc((size_t)2 * M_B * H_DIM * 4);
    unsigned int* flags = (unsigned int*)alloc(4096);             // 32 rings x 128B
    size_t base_used = (size_t)(p - (char*)d_ws);

    // Largest time-chunk whose f32 PRE buffer fits the remaining workspace.
    int TC = 0;
    const int tcs[8] = {128, 64, 32, 16, 8, 4, 2, 1};
    for (int i = 0; i < 8; ++i) {
        size_t need = base_used + (size_t)2 * tcs[i] * M_B * G4 * 4;
        if (need <= ws_size) { TC = tcs[i]; break; }
    }
    if (TC == 0) return;  // cannot run at all
    float* PREc = (float*)p;
    const int TCR = TC * M_B;

    hipMemsetAsync(flags, 0, 4096, stream);
    permute_all_kernel<<<dim3(2 * 2 * G4), 256, 0, stream>>>(
        Wih0, Whh0, b0, Wih1, Whh1, b1, Wih0p, Whh0p, Wih1p, Whh1p, b0p, b1p);
    embed_kernel<<<dim3(N_ROWS), 256, 0, stream>>>(F, emb, F_lens, X0, srcrow);

    for (int layer = 0; layer < 2; ++layer) {
        const bf16_t* Xin  = layer ? H1 : X0;
        const bf16_t* Wihp = layer ? Wih1p : Wih0p;
        const bf16_t* Whhp = layer ? Whh1p : Whh0p;
        const float*  bp   = layer ? b1p : b0p;

        hipMemsetAsync(hbA, 0, (size_t)2 * M_B * H_DIM * 2, stream);
        hipMemsetAsync(cfb, 0, (size_t)2 * M_B * H_DIM * 4, stream);

        for (int c = 0; c < S_LEN / TC; ++c) {
            gemm_pre_kernel<<<dim3(2 * (TCR / BM) * 16), 256, 0, stream>>>(
                Xin, Wihp, bp, srcrow, PREc, c * TCR, TCR);

            lstm_chunk_kernel<<<dim3(32, 4, 2), dim3(256), 0, stream>>>(
                Whhp, PREc, F_lens, cfb, hbA, hbB, H1, OUT, flags,
                c * TC, TC, TCR, layer, layer * S_LEN + c * TC);
        }
    }
}

// Round 14
// 2320.236 us; speedup vs baseline: 2.4813x; 1.0349x over previous
//
#include <hip/hip_runtime.h>
#include <hip/hip_bf16.h>

// Problem dims
#define S_LEN 128
#define M_B   256
#define E_DIM 1024
#define H_DIM 512
#define G4    2048          // 4*H
#define N_ROWS (S_LEN*M_B)  // 32768
#define KD    1024          // GEMM K for both layers (E = 2H = 1024)

typedef __bf16 bf16_t;
typedef __bf16 bf16x8 __attribute__((ext_vector_type(8)));
typedef float  f32x4  __attribute__((ext_vector_type(4)));
typedef int    i32x4  __attribute__((ext_vector_type(4)));

#define AS1(p) ((const __attribute__((address_space(1))) void*)(p))
#define AS3(p) ((__attribute__((address_space(3))) void*)(p))

__device__ __forceinline__ float sigm(float x)     { return 1.f / (1.f + __expf(-x)); }
__device__ __forceinline__ float tanhfast(float x) { return 2.f / (1.f + __expf(-2.f * x)) - 1.f; }

// Device-scope (LLC) h exchange: write-through stores, cache-bypassing loads.
__device__ __forceinline__ void store_h_dev(bf16_t* p, bf16_t v) {
    unsigned int w = (unsigned int)__builtin_bit_cast(unsigned short, v);
    asm volatile("global_store_short %0, %1, off sc0 sc1" :: "v"(p), "v"(w) : "memory");
}
__device__ __forceinline__ bf16x8 load_h_dev(const bf16_t* p) {
    i32x4 r;
    asm volatile("global_load_dwordx4 %0, %1, off sc0 sc1" : "=v"(r) : "v"(p) : "memory");
    return __builtin_bit_cast(bf16x8, r);
}
// Plain f32x4 load via asm: issues where written (not sunk to use point).
__device__ __forceinline__ f32x4 load_pv4(const float* p) {
    f32x4 r;
    asm volatile("global_load_dwordx4 %0, %1, off" : "=v"(r) : "v"(p) : "memory");
    return r;
}
// Flag barrier primitives (plain stores/loads, LLC-coherent, no RMW).
__device__ __forceinline__ void store_flag(unsigned int* p, unsigned int v) {
    asm volatile("global_store_dword %0, %1, off sc0 sc1" :: "v"(p), "v"(v) : "memory");
}
__device__ __forceinline__ unsigned int load_flag(const unsigned int* p) {
    unsigned int r;
    asm volatile("global_load_dword %0, %1, off sc0 sc1\n\ts_waitcnt vmcnt(0)"
                 : "=v"(r) : "v"(p) : "memory");
    return r;
}

// ---------------------------------------------------------------------------
// Weight permutation + bf16 conversion, BOTH layers in one launch.
// Gate permutation: j' = q*64 + gate*16 + u16  <->  j = gate*512 + (q*16+u16)
// ---------------------------------------------------------------------------
__global__ __launch_bounds__(256)
void permute_all_kernel(const float* __restrict__ Wih0, const float* __restrict__ Whh0,
                        const float* __restrict__ b0,
                        const float* __restrict__ Wih1, const float* __restrict__ Whh1,
                        const float* __restrict__ b1,
                        bf16_t* __restrict__ Wih0p, bf16_t* __restrict__ Whh0p,
                        bf16_t* __restrict__ Wih1p, bf16_t* __restrict__ Whh1p,
                        float* __restrict__ b0p, float* __restrict__ b1p)
{
    int bid = blockIdx.x;            // lay*4096 + d*2048 + jp
    int lay = bid >> 12;
    int d   = (bid >> 11) & 1;
    int jp  = bid & 2047;
    int q = jp >> 6, r = jp & 63;
    int gate = r >> 4, u16 = r & 15;
    int j = gate * H_DIM + q * 16 + u16;

    const float* Wih = lay ? Wih1 : Wih0;
    const float* Whh = lay ? Whh1 : Whh0;
    const float* b   = lay ? b1 : b0;
    bf16_t* Wihp = lay ? Wih1p : Wih0p;
    bf16_t* Whhp = lay ? Whh1p : Whh0p;
    float*  bp   = lay ? b1p : b0p;

    const float* s_ih = Wih + ((size_t)d * G4 + j) * E_DIM;
    bf16_t*      d_ih = Wihp + ((size_t)d * G4 + jp) * E_DIM;
    for (int e = threadIdx.x; e < E_DIM; e += 256) d_ih[e] = (bf16_t)s_ih[e];

    const float* s_hh = Whh + ((size_t)d * G4 + j) * H_DIM;
    bf16_t*      d_hh = Whhp + ((size_t)d * G4 + jp) * H_DIM;
    for (int k = threadIdx.x; k < H_DIM; k += 256) d_hh[k] = (bf16_t)s_hh[k];

    if (threadIdx.x == 0) bp[d * G4 + jp] = b[d * G4 + j];
}

// ---------------------------------------------------------------------------
// Embedding lookup -> bf16 X (32768 x 1024), with rowmap fused (tid 0).
// srcrow[t*256+m] = ((t < L) ? L-1-t : t) * 256 + m   (self-inverse gather)
// ---------------------------------------------------------------------------
__global__ __launch_bounds__(256)
void embed_kernel(const int* __restrict__ F, const float* __restrict__ emb,
                  const int* __restrict__ F_lens,
                  bf16_t* __restrict__ X, int* __restrict__ srcrow)
{
    int n   = blockIdx.x;            // t*256 + m
    int tok = F[n];
    const float4* src = (const float4*)(emb + (size_t)tok * E_DIM);
    bf16_t*       dst = X + (size_t)n * E_DIM;
    for (int i = threadIdx.x; i < E_DIM / 4; i += 256) {
        float4 v = src[i];
        dst[i * 4 + 0] = (bf16_t)v.x;
        dst[i * 4 + 1] = (bf16_t)v.y;
        dst[i * 4 + 2] = (bf16_t)v.z;
        dst[i * 4 + 3] = (bf16_t)v.w;
    }
    if (threadIdx.x == 0) {
        int t = n >> 8, m = n & 255;
        int L = F_lens[m];
        int st = (t < L) ? (L - 1 - t) : t;
        srcrow[n] = st * M_B + m;
    }
}

// ---------------------------------------------------------------------------
// Chunked input-projection GEMM, BK=64, XOR-swizzled LDS, XCD-chunked block
// swizzle. PRE output layout: [d][r][unit 512][gate 4] f32 — one float4 per
// (row, unit), bias folded in (vectorized consumer reads).
// ---------------------------------------------------------------------------
#define BM 128
#define BN 128
#define BKG 64

__global__ __launch_bounds__(256)
void gemm_pre_kernel(const bf16_t* __restrict__ A,    // (32768, 1024) bf16
                     const bf16_t* __restrict__ Wp,   // (2, 2048, 1024) bf16
                     const float* __restrict__ bp,    // (2, 2048)
                     const int* __restrict__ srcrow,  // (32768)
                     float* __restrict__ PREc,        // (2, TCR, 512, 4) f32
                     int rowbase, int TCR)
{
    // Bijective XCD-chunk swizzle (nwg % 8 == 0).
    const int nwg = gridDim.x;
    const int qx  = nwg >> 3;
    const int orig = blockIdx.x;
    const int wg   = (orig & 7) * qx + (orig >> 3);
    const int MT   = TCR / BM;
    const int n_t  = wg & 15;
    const int m_t  = (wg >> 4) % MT;
    const int d    = wg / (16 * MT);

    const int n0   = n_t * BN;
    const int mloc = m_t * BM;
    const int tid  = threadIdx.x;
    const int lane = tid & 63, wave = tid >> 6;
    const int wm = wave >> 1, wn = wave & 1;
    const int fr = lane & 15, fq = lane >> 4;

    __shared__ __attribute__((aligned(16))) bf16_t At[BM * BKG];   // 16 KiB
    __shared__ __attribute__((aligned(16))) bf16_t Bt[BN * BKG];   // 16 KiB

    // Staging: per thread 4 A-rows + 4 B-rows (rows rA + 32*it), fixed source
    // column-chunk co = swizzled by row (pre-swizzled source, linear dest).
    const int rA = tid >> 3;                           // 0..31
    const int co = (((tid & 7) ^ (rA & 7)) << 3);      // element offset in row
    size_t srowA[4];
    const bf16_t* Bp[4];
#pragma unroll
    for (int it = 0; it < 4; ++it) {
        int nn = rowbase + mloc + rA + it * 32;
        srowA[it] = (d == 1) ? (size_t)srcrow[nn] : (size_t)nn;
        Bp[it] = Wp + ((size_t)d * G4 + n0 + rA + it * 32) * KD + co;
    }

    f32x4 acc[4][4];
#pragma unroll
    for (int i = 0; i < 4; ++i)
#pragma unroll
        for (int j = 0; j < 4; ++j) { f32x4 z = {0.f, 0.f, 0.f, 0.f}; acc[i][j] = z; }

    for (int kt = 0; kt < KD; kt += BKG) {
#pragma unroll
        for (int it = 0; it < 4; ++it)
            __builtin_amdgcn_global_load_lds(AS1(A + srowA[it] * KD + kt + co),
                                             AS3(&At[(it * 256 + wave * 64) * 8]), 16, 0, 0);
#pragma unroll
        for (int it = 0; it < 4; ++it)
            __builtin_amdgcn_global_load_lds(AS1(Bp[it] + kt),
                                             AS3(&Bt[(it * 256 + wave * 64) * 8]), 16, 0, 0);
        __syncthreads();

        bf16x8 af[2][4], bff[2][4];
#pragma unroll
        for (int ks = 0; ks < 2; ++ks) {
#pragma unroll
            for (int i = 0; i < 4; ++i) {
                int ra = wm * 64 + i * 16 + fr;
                int ca = (ks * 4 + fq) ^ (ra & 7);
                af[ks][i] = *(const bf16x8*)&At[ra * BKG + ca * 8];
                int rb = wn * 64 + i * 16 + fr;
                int cbk = (ks * 4 + fq) ^ (rb & 7);
                bff[ks][i] = *(const bf16x8*)&Bt[rb * BKG + cbk * 8];
            }
        }
#pragma unroll
        for (int ks = 0; ks < 2; ++ks)
#pragma unroll
            for (int i = 0; i < 4; ++i)
#pragma unroll
                for (int j = 0; j < 4; ++j)
                    acc[i][j] = __builtin_amdgcn_mfma_f32_16x16x32_bf16(af[ks][i], bff[ks][j], acc[i][j], 0, 0, 0);
        __syncthreads();
    }

    // Epilogue: gate-interleaved float4 store. unit = ((n0>>6)+wn)*16 + fr,
    // gate g = old col n0+wn*64+fr+g*16 (bias folded here).
    const int ucol = ((n0 >> 6) + wn) * 16 + fr;
    float bq[4];
#pragma unroll
    for (int g = 0; g < 4; ++g) bq[g] = bp[d * G4 + n0 + wn * 64 + fr + g * 16];
#pragma unroll
    for (int mi = 0; mi < 4; ++mi) {
#pragma unroll
        for (int rr = 0; rr < 4; ++rr) {
            int r = mloc + wm * 64 + mi * 16 + fq * 4 + rr;
            f32x4 v;
#pragma unroll
            for (int g = 0; g < 4; ++g) v[g] = acc[mi][g][rr] + bq[g];
            *(f32x4*)&PREc[(((size_t)d * TCR + r) * 512 + ucol) * 4] = v;
        }
    }
}

// ---------------------------------------------------------------------------
// Persistent recurrence kernel with TWO-TIER BARRIER:
//  tier 1 (intra-block, LDS): each wave, after draining its own h stores
//    (vmcnt is per-wave), posts arr[wave]=tag. Waves 1-3 then spin ONLY on
//    the LDS `go` word (lgkmcnt domain) — their pv prefetch stays in flight
//    across the barrier and is drained by the NEXT step's h-load vmcnt(0).
//  tier 2 (inter-block, wave 0 only): wave 0 gathers arrivals, writes one
//    block-flag (sc0sc1), vector-polls the 32 block-flags of its (my,d)
//    group (vmcnt(0) drains only wave 0's loads), then publishes `go`.
// Ordering: h stores ack@LLC -> arr -> flag -> partner sees flag -> go ->
// partner h loads (same release chain as proven R6..R13 design).
// ---------------------------------------------------------------------------
__global__ __launch_bounds__(256)
void lstm_chunk_kernel(const bf16_t* __restrict__ Whhp,  // (2,2048,512) bf16
                       const float* __restrict__ PREc,   // (2,TCR,512,4) f32
                       const int* __restrict__ F_lens,
                       float* __restrict__ cfb,          // (2,256,512) f32
                       bf16_t* __restrict__ hbA,         // (2,256,512) bf16
                       bf16_t* __restrict__ hbB,         // (2,256,512) bf16
                       bf16_t* __restrict__ H1,          // (32768,1024) bf16 (mode 0)
                       float* __restrict__ OUT,          // (32768,1024) f32  (mode 1)
                       unsigned int* __restrict__ flags, // 8 groups x 32 x u32 (128B/group)
                       int t0, int TC, int TCR, int mode, int s_base)
{
    const int d  = blockIdx.z;
    const int bx = blockIdx.x;          // unit group 0..31
    const int m0 = blockIdx.y * 64;
    const int tid = threadIdx.x;
    const int lane = tid & 63, wave = tid >> 6;
    const int fr = lane & 15, fq = lane >> 4;
    // Group = (my, d): 32 blocks; one flag dword per block in a 128B line.
    unsigned int* gflags = flags + (((blockIdx.y << 1) | d) << 5);

    __shared__ __attribute__((aligned(16))) bf16_t Bt[64 * 512];   // 64 KiB
    __shared__ unsigned int arr[4];
    __shared__ unsigned int go_w;

    // Stage Whh slice (64 rows x 512 K) once; XOR-swizzled SOURCE, linear dest.
    const bf16_t* Bg = Whhp + ((size_t)d * G4 + bx * 64) * H_DIM;
#pragma unroll
    for (int it = 0; it < 16; ++it) {
        int c   = it * 256 + tid;
        int row = c >> 6, ck = c & 63;
        int cks = ck ^ (row & 7);
        __builtin_amdgcn_global_load_lds(AS1(Bg + (size_t)row * H_DIM + cks * 8),
                                         AS3(&Bt[(it * 256 + wave * 64) * 8]), 16, 0, 0);
    }

    if (tid < 4) __hip_atomic_store(&arr[tid], (unsigned int)s_base,
                                    __ATOMIC_RELAXED, __HIP_MEMORY_SCOPE_WORKGROUP);
    if (tid == 0) __hip_atomic_store(&go_w, (unsigned int)s_base,
                                     __ATOMIC_RELAXED, __HIP_MEMORY_SCOPE_WORKGROUP);

    // Per-lane constants (lane owns unit u for 4 fixed m-rows, all steps).
    const int mrow  = m0 + wave * 16 + fr;     // A-fragment row
    const int u     = bx * 16 + fr;
    int mm[4], LL[4], sidx[4];
    float c_own[4], h_own[4];
    const float* pbase[4];
#pragma unroll
    for (int rr = 0; rr < 4; ++rr) {
        mm[rr]   = m0 + wave * 16 + fq * 4 + rr;
        LL[rr]   = F_lens[mm[rr]];
        sidx[rr] = (d * M_B + mm[rr]) * H_DIM + u;
        c_own[rr]= cfb[sidx[rr]];
        pbase[rr]= PREc + (((size_t)d * TCR + mm[rr]) * 512 + u) * 4;
    }
    {
        const bf16_t* hin0 = (t0 & 1) ? hbB : hbA;
#pragma unroll
        for (int rr = 0; rr < 4; ++rr) h_own[rr] = (float)hin0[sidx[rr]];
    }

    // pv for step 0 (one float4 per rr).
    f32x4 pv[4];
#pragma unroll
    for (int rr = 0; rr < 4; ++rr)
        pv[rr] = load_pv4(pbase[rr]);

    __syncthreads();   // staging + pv + LDS init all visible

    for (int tt = 0; tt < TC; ++tt) {
        const int t = t0 + tt;
        const unsigned int tgt = (unsigned int)(s_base + tt + 1);
        const bf16_t* hin  = (t & 1) ? hbB : hbA;
        bf16_t*       hout = (t & 1) ? hbA : hbB;

        // h fragments (device-scope, bypass L1/L2 -> LLC where producers wrote).
        // This vmcnt(0) also retires last step's pv prefetch (full-step overlap).
        const bf16_t* Arow = hin + ((size_t)d * M_B + mrow) * H_DIM + fq * 8;
        bf16x8 af[16];
#pragma unroll
        for (int ks = 0; ks < 16; ++ks)
            af[ks] = load_h_dev(Arow + ks * 32);
        asm volatile("s_waitcnt vmcnt(0)" ::: "memory");
        __builtin_amdgcn_sched_barrier(0);

        f32x4 acc[4];
#pragma unroll
        for (int j = 0; j < 4; ++j) { f32x4 z = {0.f, 0.f, 0.f, 0.f}; acc[j] = z; }

#pragma unroll
        for (int ks = 0; ks < 16; ++ks) {
#pragma unroll
            for (int j = 0; j < 4; ++j) {
                int rb = j * 16 + fr;
                int ck = (ks * 4 + fq) ^ (rb & 7);
                bf16x8 bf = *(const bf16x8*)&Bt[rb * 512 + ck * 8];
                acc[j] = __builtin_amdgcn_mfma_f32_16x16x32_bf16(af[ks], bf, acc[j], 0, 0, 0);
            }
        }

        // LSTM cell + h stores (critical path).
#pragma unroll
        for (int rr = 0; rr < 4; ++rr) {
            bool mt = (t < LL[rr]);
            float gi = acc[0][rr] + pv[rr][0];
            float gf = acc[1][rr] + pv[rr][1];
            float gg = acc[2][rr] + pv[rr][2];
            float go = acc[3][rr] + pv[rr][3];
            float c2 = sigm(gf) * c_own[rr] + sigm(gi) * tanhfast(gg);
            float h2 = sigm(go) * tanhfast(c2);
            if (!mt) { c2 = c_own[rr]; h2 = h_own[rr]; }
            c_own[rr] = c2;
            h_own[rr] = h2;
            store_h_dev(&hout[sidx[rr]], (bf16_t)h2);
        }
        asm volatile("s_waitcnt vmcnt(0)" ::: "memory");  // this wave's h stores @LLC
        if (lane == 0)
            __hip_atomic_store(&arr[wave], tgt, __ATOMIC_RELAXED, __HIP_MEMORY_SCOPE_WORKGROUP);

        // Shadow phase: output stores + next-step PRE prefetch (rides across barrier).
#pragma unroll
        for (int rr = 0; rr < 4; ++rr) {
            bool mt = (t < LL[rr]);
            int trow = (d == 0 || !mt) ? t : (LL[rr] - 1 - t);
            size_t orow = (size_t)trow * M_B + mm[rr];
            if (mode == 0) H1[orow * 1024 + d * H_DIM + u] = (bf16_t)h_own[rr];
            else           OUT[orow * 1024 + d * H_DIM + u] = mt ? h_own[rr] : 0.f;
        }
        f32x4 pvn[4];
        if (tt + 1 < TC) {
#pragma unroll
            for (int rr = 0; rr < 4; ++rr)
                pvn[rr] = load_pv4(pbase[rr] + (size_t)(tt + 1) * ((size_t)M_B * G4));
        }

        // Two-tier barrier.
        if (wave == 0) {
            // Gather intra-block arrivals (LDS broadcast reads, uniform exit).
            for (;;) {
                unsigned int a0 = __hip_atomic_load(&arr[0], __ATOMIC_RELAXED, __HIP_MEMORY_SCOPE_WORKGROUP);
                unsigned int a1 = __hip_atomic_load(&arr[1], __ATOMIC_RELAXED, __HIP_MEMORY_SCOPE_WORKGROUP);
                unsigned int a2 = __hip_atomic_load(&arr[2], __ATOMIC_RELAXED, __HIP_MEMORY_SCOPE_WORKGROUP);
                unsigned int a3 = __hip_atomic_load(&arr[3], __ATOMIC_RELAXED, __HIP_MEMORY_SCOPE_WORKGROUP);
                unsigned int mn = min(min(a0, a1), min(a2, a3));
                if (mn >= tgt) break;
                __builtin_amdgcn_s_sleep(1);
            }
            if (lane == 0) store_flag(&gflags[bx], tgt);
            const unsigned int* fp = &gflags[lane & 31];
            while (__ballot(load_flag(fp) >= tgt) != ~0ull)
                __builtin_amdgcn_s_sleep(1);
            if (lane == 0)
                __hip_atomic_store(&go_w, tgt, __ATOMIC_RELAXED, __HIP_MEMORY_SCOPE_WORKGROUP);
        } else {
            // Pure-LDS spin (lgkmcnt): this wave's pv prefetch stays in flight.
            while (__hip_atomic_load(&go_w, __ATOMIC_RELAXED, __HIP_MEMORY_SCOPE_WORKGROUP) < tgt)
                __builtin_amdgcn_s_sleep(1);
        }

        if (tt + 1 < TC) {
#pragma unroll
            for (int rr = 0; rr < 4; ++rr)
                pv[rr] = pvn[rr];
        }
    }

#pragma unroll
    for (int rr = 0; rr < 4; ++rr) cfb[sidx[rr]] = c_own[rr];
}

// ---------------------------------------------------------------------------
extern "C" void kernel_launch(void* const* d_in, const int* in_sizes, int n_in,
                              void* d_out, int out_size, void* d_ws, size_t ws_size,
                              hipStream_t stream)
{
    const int*   F      = (const int*)d_in[0];
    const int*   F_lens = (const int*)d_in[1];
    const float* emb    = (const float*)d_in[2];
    const float* Wih0   = (const float*)d_in[3];
    const float* Whh0   = (const float*)d_in[4];
    const float* b0     = (const float*)d_in[5];
    const float* Wih1   = (const float*)d_in[6];
    const float* Whh1   = (const float*)d_in[7];
    const float* b1     = (const float*)d_in[8];
    float* OUT = (float*)d_out;

    // Base workspace (~155 MiB), 256B-aligned blocks.
    char* p = (char*)d_ws;
    auto alloc = [&](size_t bytes) { char* q = p; p += (bytes + 255) & ~(size_t)255; return (void*)q; };
    bf16_t* X0    = (bf16_t*)alloc((size_t)N_ROWS * E_DIM * 2);   // 64 MiB
    bf16_t* H1    = (bf16_t*)alloc((size_t)N_ROWS * 1024 * 2);    // 64 MiB
    bf16_t* Wih0p = (bf16_t*)alloc((size_t)2 * G4 * E_DIM * 2);   // 8 MiB
    bf16_t* Whh0p = (bf16_t*)alloc((size_t)2 * G4 * H_DIM * 2);   // 4 MiB
    bf16_t* Wih1p = (bf16_t*)alloc((size_t)2 * G4 * E_DIM * 2);   // 8 MiB
    bf16_t* Whh1p = (bf16_t*)alloc((size_t)2 * G4 * H_DIM * 2);   // 4 MiB
    float*  b0p   = (float*)alloc((size_t)2 * G4 * 4);
    float*  b1p   = (float*)alloc((size_t)2 * G4 * 4);
    int*    srcrow= (int*)alloc((size_t)N_ROWS * 4);              // 128 KiB
    bf16_t* hbA   = (bf16_t*)alloc((size_t)2 * M_B * H_DIM * 2);
    bf16_t* hbB   = (bf16_t*)alloc((size_t)2 * M_B * H_DIM * 2);
    float*  cfb   = (float*)alloc((size_t)2 * M_B * H_DIM * 4);
    unsigned int* flags = (unsigned int*)alloc(4096);             // 8 groups x 128B
    size_t base_used = (size_t)(p - (char*)d_ws);

    // Largest time-chunk whose f32 PRE buffer fits the remaining workspace.
    int TC = 0;
    const int tcs[8] = {128, 64, 32, 16, 8, 4, 2, 1};
    for (int i = 0; i < 8; ++i) {
        size_t need = base_used + (size_t)2 * tcs[i] * M_B * G4 * 4;
        if (need <= ws_size) { TC = tcs[i]; break; }
    }
    if (TC == 0) return;  // cannot run at all
    float* PREc = (float*)p;
    const int TCR = TC * M_B;

    hipMemsetAsync(flags, 0, 4096, stream);
    permute_all_kernel<<<dim3(2 * 2 * G4), 256, 0, stream>>>(
        Wih0, Whh0, b0, Wih1, Whh1, b1, Wih0p, Whh0p, Wih1p, Whh1p, b0p, b1p);
    embed_kernel<<<dim3(N_ROWS), 256, 0, stream>>>(F, emb, F_lens, X0, srcrow);

    for (int layer = 0; layer < 2; ++layer) {
        const bf16_t* Xin  = layer ? H1 : X0;
        const bf16_t* Wihp = layer ? Wih1p : Wih0p;
        const bf16_t* Whhp = layer ? Whh1p : Whh0p;
        const float*  bp   = layer ? b1p : b0p;

        hipMemsetAsync(hbA, 0, (size_t)2 * M_B * H_DIM * 2, stream);
        hipMemsetAsync(cfb, 0, (size_t)2 * M_B * H_DIM * 4, stream);

        for (int c = 0; c < S_LEN / TC; ++c) {
            gemm_pre_kernel<<<dim3(2 * (TCR / BM) * 16), 256, 0, stream>>>(
                Xin, Wihp, bp, srcrow, PREc, c * TCR, TCR);

            lstm_chunk_kernel<<<dim3(32, 4, 2), dim3(256), 0, stream>>>(
                Whhp, PREc, F_lens, cfb, hbA, hbB, H1, OUT, flags,
                c * TC, TC, TCR, layer, layer * S_LEN + c * TC);
        }
    }
}